// Round 9
// baseline (141.559 us; speedup 1.0000x reference)
//
#include <hip/hip_runtime.h>
#include <cstdint>

// StreamNet K3 S1 halo conv, bf16 MFMA implicit-GEMM.
// R14: cross-tile software pipeline. Model (R6..R13): ~all x reads are
// L2-miss/LLC-hit (x=67MB > 32MB L2, read-once; FETCH only counts HBM), and
// every variant's duration == LLC-read volume / ~2.5 TB/s regardless of
// occupancy/width/depth -> the Infinity-Cache read path (~2.5-3 TB/s) is the
// wall; floor = 67MB/2.75 ~= 25-28us. The ~15us gap to 41us is read-idle
// time during each block's pack/MFMA/store convoy (1 tile/block, all blocks
// launch-aligned -> no stagger). Fix: grid 512, 2 adjacent tiles per block
// (cx even/odd pair, same batch/XCD; T1 left halo = T0 right edge, L2-hot);
// T1's 24 global loads fly DURING T0's MFMA sweeps; single LDS buffer.
// Order Bf+bias loads FIRST so later per-k2 vmcnt waits never re-drain them;
// T1 prefetch split around the ch0 sweep to cap live set ~185 VGPR
// (plain (256,2) only -- R7/R10/R11: min-occupancy >=3 => RA squeeze+spill).
// Keeps R13: pack_w prologue, Bf direct-from-global (L1), 16x32 tiles,
// RS=34/PL=612 LDS 39168B, XCD swizzle (batch i -> XCD i), ch-split sweep,
// plain f4 epilogue stores, b64 interior LDS stores.
//
// Padded input Xp[b][c][r][cc], r,cc in [0,258):
//   r < 2           -> bbuf[b][c][r][cc]           (bbuf [B][C][2][258])
//   r>=2, cc < 2    -> rbuf[b][c][r-2][cc]         (rbuf [B][C][256][2])
//   r>=2, cc>=2     -> (cc-2 == 255) ? 0 : x[b][c][r-2][cc-2]

constexpr int B  = 8;
constexpr int C  = 32;
constexpr int P  = 256;
constexpr int KB = 2;
constexpr int TH = 16;            // tile rows
constexpr int TW = 32;            // tile cols
constexpr int RS = 34;            // LDS row stride (dwords) == padded width
constexpr int PL = 612;           // plane stride (dwords); 4q*612 mod 32 = {0,16} -> 2-way, free
constexpr int XSZ = 16 * PL;      // 9792 dwords = 39168 B

typedef short bf16x8 __attribute__((ext_vector_type(8)));
typedef float f32x4  __attribute__((ext_vector_type(4)));
union Frag { uint32_t u[4]; bf16x8 v; };

static __device__ __forceinline__ uint32_t pk_bf16(float lo, float hi) {
    uint32_t a  = __builtin_bit_cast(uint32_t, lo);
    uint32_t b2 = __builtin_bit_cast(uint32_t, hi);
    a  += 0x7FFFu + ((a  >> 16) & 1u);
    b2 += 0x7FFFu + ((b2 >> 16) & 1u);
    return (a >> 16) | (b2 & 0xFFFF0000u);
}

// ---- prologue: pack W [C][C][3][3] f32 -> bf16-pair image in d_ws ----
// image dword index: t*512 + oc*16 + icpair, halves (lo,hi) = ic (2m, 2m+1)
__global__ __launch_bounds__(256) void pack_w_kernel(
    const float* __restrict__ W, uint32_t* __restrict__ wpk)
{
    const int g = blockIdx.x * 256 + threadIdx.x;      // 0..2303
    const float4 v = ((const float4*)W)[g];
    const float vv[4] = { v.x, v.y, v.z, v.w };
    uint16_t* wh = (uint16_t*)wpk;
    #pragma unroll
    for (int e = 0; e < 4; ++e) {
        const int flat = 4 * g + e;                    // (oc*32+ic)*9 + t
        const int t    = flat % 9;
        const int rest = flat / 9;
        const int ic   = rest & 31;
        const int oc   = rest >> 5;
        const uint32_t u = __builtin_bit_cast(uint32_t, vv[e]);
        const uint16_t h = (uint16_t)((u + 0x7FFFu + ((u >> 16) & 1u)) >> 16);
        wh[(t * 512 + oc * 16 + (ic >> 1)) * 2 + (ic & 1)] = h;
    }
}

struct StP {                       // one plane-pair's staged data
    float4 a0, a1, c0, c1;         // interior: lo plane 8 cols, hi plane 8 cols
    float  h0l, h0h, h1l, h1h;     // 2 halo cells x (lo, hi)
};

__global__ __launch_bounds__(256, 2) void conv_mfma(
    const float* __restrict__ x,      // [B][C][P][P]
    const float* __restrict__ rbuf,   // [B][C][P][KB]
    const float* __restrict__ bbuf,   // [B][C][KB][P+KB]
    const uint32_t* __restrict__ wpk, // packed W image (4608 dwords, fits L1)
    const float* __restrict__ bias,   // [C]
    float* __restrict__ out)          // [B][C][P][P]
{
    const int tid  = threadIdx.x;
    const int lane = tid & 63;
    const int w    = tid >> 6;        // wave 0..3
    const int q    = lane >> 4;
    const int n16  = lane & 15;

    // XCD swizzle: 512 blocks round-robin -> XCD i gets sw [64i,64(i+1)) =
    // all tile-pairs of batch i. Pair = tiles (cx0, cx0+1) of same (b,ty).
    const int sw  = (blockIdx.x & 7) * 64 + (blockIdx.x >> 3);
    const int b   = sw >> 6;
    const int ty  = (sw >> 2) & 15;
    const int cx0 = 2 * (sw & 3);               // even: 0,2,4,6
    const int x00 = cx0 * TW, x01 = x00 + TW, y0 = ty * TH;

    __shared__ uint32_t Xs[XSZ];

    // ---- staging lane geometry ----
    const int srow = lane >> 2;                 // 0..15
    const int scol = (lane & 3) * 8;            // 0,8,16,24 (8 cols/lane)

    // halo lane constants (x0-independent): 100 cells = top 2x34 + left 16x2
    int prowA[2], pcolA[2], h_ldso[2];
    #pragma unroll
    for (int ci = 0; ci < 2; ++ci) {
        const int c = lane + 64 * ci;
        int prow, pcol;
        if (c < 68) { const int hr = (c >= 34) ? 1 : 0; prow = hr; pcol = c - 34 * hr; }
        else        { const int cc = c - 68; prow = KB + (cc >> 1); pcol = cc & 1; }
        prowA[ci] = prow; pcolA[ci] = pcol;
        h_ldso[ci] = prow * RS + pcol;
    }
    const bool h1a = lane < 36;                 // cell1 active

    const float* xb = x    + (size_t)b * C * P * P;
    const float* rb = rbuf + (size_t)b * C * P * KB;
    const float* bb = bbuf + (size_t)b * C * KB * (P + KB);
    const float* basep[3] = { xb, rb, bb };
    const int    psz[3]   = { P * P, P * KB, KB * (P + KB) };

    auto mkh = [&](int x0, const float** bp, int* ps, bool* z) {
        #pragma unroll
        for (int ci = 0; ci < 2; ++ci) {
            const int gr = y0 + prowA[ci], gc = x0 + pcolA[ci];
            int sel, off; bool zz = false;
            if (gr < KB)      { sel = 2; off = gr * (P + KB) + gc; }
            else if (gc < KB) { sel = 1; off = (gr - KB) * KB + gc; }
            else              { sel = 0; off = (gr - KB) * P + (gc - KB);
                                zz = (gc == P + KB - 1); }
            bp[ci] = basep[sel] + off;
            ps[ci] = psz[sel];
            z[ci]  = zz;
        }
    };

    auto ldp = [&](int m, int x0, const float* const* bp, const int* ps,
                   const bool* z, StP& S) {
        const float* pi = xb + (size_t)(2 * m) * (P * P) + (y0 + srow) * P + x0 + scol;
        S.a0 = *(const float4*)pi;
        S.a1 = *(const float4*)(pi + 4);
        S.c0 = *(const float4*)(pi + P * P);
        S.c1 = *(const float4*)(pi + P * P + 4);
        const float* p0 = bp[0] + (size_t)(2 * m) * ps[0];
        S.h0l = z[0] ? 0.f : p0[0];
        S.h0h = z[0] ? 0.f : p0[ps[0]];
        if (h1a) {
            const float* p1 = bp[1] + (size_t)(2 * m) * ps[1];
            S.h1l = z[1] ? 0.f : p1[0];
            S.h1h = z[1] ? 0.f : p1[ps[1]];
        }
    };

    auto stp = [&](int m, const StP& S, bool zcc) {
        float4 a1 = S.a1, c1 = S.c1;
        if (zcc) { a1.w = 0.f; c1.w = 0.f; }
        uint2 p0, p1, p2, p3;
        p0.x = pk_bf16(S.a0.x, S.c0.x); p0.y = pk_bf16(S.a0.y, S.c0.y);
        p1.x = pk_bf16(S.a0.z, S.c0.z); p1.y = pk_bf16(S.a0.w, S.c0.w);
        p2.x = pk_bf16(a1.x, c1.x);     p2.y = pk_bf16(a1.y, c1.y);
        p3.x = pk_bf16(a1.z, c1.z);     p3.y = pk_bf16(a1.w, c1.w);
        uint32_t* base = Xs + m * PL + (srow + KB) * RS + KB + scol;  // 8B aligned
        *(uint2*)(base + 0) = p0;
        *(uint2*)(base + 2) = p1;
        *(uint2*)(base + 4) = p2;
        *(uint2*)(base + 6) = p3;
        Xs[m * PL + h_ldso[0]] = pk_bf16(S.h0l, S.h0h);
        if (h1a) Xs[m * PL + h_ldso[1]] = pk_bf16(S.h1l, S.h1h);
    };

    // ---- 1. Bf + bias FIRST (L1-fast; oldest in vmcnt FIFO, so later
    //         per-k2 staging waits never stall on them being newest) ----
    Frag Bf[9][2];
    #pragma unroll
    for (int t = 0; t < 9; ++t)
        #pragma unroll
        for (int oh = 0; oh < 2; ++oh)
            *(uint4*)Bf[t][oh].u =
                *(const uint4*)&wpk[t * 512 + (oh * 16 + n16) * 16 + q * 4];
    const float bv0 = bias[n16];
    const float bv1 = bias[16 + n16];

    // ---- MFMA sweep for one column-half of one tile + epilogue ----
    auto mfma_ch = [&](int ch, int x0) {
        f32x4 acc[4][2];
        #pragma unroll
        for (int rr = 0; rr < 4; ++rr)
            #pragma unroll
            for (int oh = 0; oh < 2; ++oh)
                #pragma unroll
                for (int e = 0; e < 4; ++e) acc[rr][oh][e] = 0.f;

        #pragma unroll
        for (int dr = 0; dr < 6; ++dr) {
            Frag A[3];
            const uint32_t* ap = Xs + (4 * q) * PL + (4 * w + dr) * RS + 16 * ch + n16;
            #pragma unroll
            for (int kx = 0; kx < 3; ++kx)
                #pragma unroll
                for (int p = 0; p < 4; ++p)
                    A[kx].u[p] = ap[p * PL + kx];
            #pragma unroll
            for (int ky = 0; ky < 3; ++ky) {
                const int rr = dr - ky;
                if (rr >= 0 && rr < 4) {
                    #pragma unroll
                    for (int kx = 0; kx < 3; ++kx) {
                        acc[rr][0] = __builtin_amdgcn_mfma_f32_16x16x32_bf16(
                                         A[kx].v, Bf[ky * 3 + kx][0].v, acc[rr][0], 0, 0, 0);
                        acc[rr][1] = __builtin_amdgcn_mfma_f32_16x16x32_bf16(
                                         A[kx].v, Bf[ky * 3 + kx][1].v, acc[rr][1], 0, 0, 0);
                    }
                }
            }
        }
        #pragma unroll
        for (int oh = 0; oh < 2; ++oh) {
            const int oc = oh * 16 + n16;
            const float bv = oh ? bv1 : bv0;
            #pragma unroll
            for (int rr = 0; rr < 4; ++rr) {
                float4 v;
                v.x = acc[rr][oh][0] + bv;
                v.y = acc[rr][oh][1] + bv;
                v.z = acc[rr][oh][2] + bv;
                v.w = acc[rr][oh][3] + bv;
                *(float4*)&out[((size_t)(b * C + oc) * P + (y0 + 4 * w + rr)) * P
                               + x0 + 16 * ch + 4 * q] = v;
            }
        }
    };

    // ---- 2. T0: load, pack, stage (cx0 even -> zc never applies) ----
    const float* bp0[2]; int ps0[2]; bool z0[2];
    mkh(x00, bp0, ps0, z0);
    StP S0[4];
    #pragma unroll
    for (int k2 = 0; k2 < 4; ++k2) ldp(4 * k2 + w, x00, bp0, ps0, z0, S0[k2]);
    #pragma unroll
    for (int k2 = 0; k2 < 4; ++k2) stp(4 * k2 + w, S0[k2], false);
    __syncthreads();

    // ---- 3. T1 prefetch (halves around ch0 sweep) || T0 MFMA ----
    const float* bp1[2]; int ps1[2]; bool z1[2];
    mkh(x01, bp1, ps1, z1);
    const bool zc1 = (x01 == P - TW) && ((lane & 3) == 3);
    StP S1[4];
    ldp(w,     x01, bp1, ps1, z1, S1[0]);
    ldp(4 + w, x01, bp1, ps1, z1, S1[1]);

    mfma_ch(0, x00);

    ldp(8 + w,  x01, bp1, ps1, z1, S1[2]);
    ldp(12 + w, x01, bp1, ps1, z1, S1[3]);

    mfma_ch(1, x00);
    __syncthreads();                 // all waves done reading Xs (T0)

    // ---- 4. stage T1 (loads long in flight), compute T1 ----
    #pragma unroll
    for (int k2 = 0; k2 < 4; ++k2) stp(4 * k2 + w, S1[k2], zc1);
    __syncthreads();

    mfma_ch(0, x01);
    mfma_ch(1, x01);
}

extern "C" void kernel_launch(void* const* d_in, const int* in_sizes, int n_in,
                              void* d_out, int out_size, void* d_ws, size_t ws_size,
                              hipStream_t stream) {
    const float* x    = (const float*)d_in[0];
    const float* rbuf = (const float*)d_in[1];
    const float* bbuf = (const float*)d_in[2];
    const float* W    = (const float*)d_in[3];
    const float* bias = (const float*)d_in[4];
    float* out = (float*)d_out;
    uint32_t* wpk = (uint32_t*)d_ws;              // 18432 B used

    pack_w_kernel<<<9, 256, 0, stream>>>(W, wpk);
    conv_mfma<<<512, 256, 0, stream>>>(x, rbuf, bbuf, wpk, bias, out);
}

// Round 10
// 140.682 us; speedup vs baseline: 1.0062x; 1.0062x over previous
//
#include <hip/hip_runtime.h>
#include <cstdint>

// StreamNet K3 S1 halo conv, bf16 MFMA implicit-GEMM.
// R15: pipelining with 4 blk/CU restored. R14's 2-tile pipeline failed at
// grid 512 (2 blk/CU, lost the 4-block stagger) + small spill. R15: grid
// 1024, block = two VERTICALLY adjacent 16x16 tiles (T1 top halo = T0
// bottom rows, L1/L2-hot). Key vmcnt insight: with Bf from GLOBAL (R13),
// consuming any newer load forces a full vmcnt drain -> kills prefetch
// queues. LDS reads use lgkmcnt (separate counter), so W goes BACK to LDS:
// MFMA sweeps touch only lgkmcnt while T1 global loads stay in flight.
// oh-split sweeps load per-oh Bf (36 transient regs via ds_read_b128) ->
// peak live set ~120 < 128 -> 4 waves/EU with plain (256,2) (R7/R10/R11:
// never use min-occupancy attrs >=3; RA squeeze = spill catastrophe).
// LDS: X 16x324=5184dw + W 4608dw = 39168B -> 4 blocks/CU.
// Pipeline: ld T0 | stage T0 | bar | ld T1[0,1] | sweep(T0,oh0) | ld T1[2]
// | sweep(T0,oh1) | ld T1[3] | bar | stage T1 | bar | sweep(T1,oh0/oh1).
// Keeps: pack_w prologue, XCD swizzle (batch i -> XCD i), plain f4 stores,
// generic per-cell halo source resolution.
//
// Padded input Xp[b][c][r][cc], r,cc in [0,258):
//   r < 2           -> bbuf[b][c][r][cc]           (bbuf [B][C][2][258])
//   r>=2, cc < 2    -> rbuf[b][c][r-2][cc]         (rbuf [B][C][256][2])
//   r>=2, cc>=2     -> (cc-2 == 255) ? 0 : x[b][c][r-2][cc-2]

constexpr int B  = 8;
constexpr int C  = 32;
constexpr int P  = 256;
constexpr int KB = 2;
constexpr int TS = 16;            // tile side
constexpr int RS = 18;            // LDS row stride (dwords) == padded width
constexpr int PL = 324;           // plane stride (dwords); 4q*324 %32 = 16/0 -> 2-way, free
constexpr int XSZ = 16 * PL;      // 5184 dwords
constexpr int WOFF = XSZ;         // W region offset
constexpr int LDSZ = XSZ + 4608;  // 9792 dwords = 39168 B -> 4 blocks/CU

typedef short bf16x8 __attribute__((ext_vector_type(8)));
typedef float f32x4  __attribute__((ext_vector_type(4)));
union Frag { uint32_t u[4]; bf16x8 v; };

static __device__ __forceinline__ uint32_t pk_bf16(float lo, float hi) {
    uint32_t a  = __builtin_bit_cast(uint32_t, lo);
    uint32_t b2 = __builtin_bit_cast(uint32_t, hi);
    a  += 0x7FFFu + ((a  >> 16) & 1u);
    b2 += 0x7FFFu + ((b2 >> 16) & 1u);
    return (a >> 16) | (b2 & 0xFFFF0000u);
}

// ---- prologue: pack W [C][C][3][3] f32 -> bf16-pair image in d_ws ----
// image dword index: t*512 + oc*16 + icpair, halves (lo,hi) = ic (2m, 2m+1)
__global__ __launch_bounds__(256) void pack_w_kernel(
    const float* __restrict__ W, uint32_t* __restrict__ wpk)
{
    const int g = blockIdx.x * 256 + threadIdx.x;      // 0..2303
    const float4 v = ((const float4*)W)[g];
    const float vv[4] = { v.x, v.y, v.z, v.w };
    uint16_t* wh = (uint16_t*)wpk;
    #pragma unroll
    for (int e = 0; e < 4; ++e) {
        const int flat = 4 * g + e;                    // (oc*32+ic)*9 + t
        const int t    = flat % 9;
        const int rest = flat / 9;
        const int ic   = rest & 31;
        const int oc   = rest >> 5;
        const uint32_t u = __builtin_bit_cast(uint32_t, vv[e]);
        const uint16_t h = (uint16_t)((u + 0x7FFFu + ((u >> 16) & 1u)) >> 16);
        wh[(t * 512 + oc * 16 + (ic >> 1)) * 2 + (ic & 1)] = h;
    }
}

struct St16 {                      // one plane-pair's staged data (16x16 tile)
    float4 a0, c0;                 // interior: lo plane, hi plane (4 cols)
    float  h0l, h0h, h1l, h1h;     // 2 halo cells x (lo, hi)
};

__global__ __launch_bounds__(256, 2) void conv_mfma(
    const float* __restrict__ x,      // [B][C][P][P]
    const float* __restrict__ rbuf,   // [B][C][P][KB]
    const float* __restrict__ bbuf,   // [B][C][KB][P+KB]
    const uint32_t* __restrict__ wpk, // packed W image (4608 dwords)
    const float* __restrict__ bias,   // [C]
    float* __restrict__ out)          // [B][C][P][P]
{
    const int tid  = threadIdx.x;
    const int lane = tid & 63;
    const int w    = tid >> 6;        // wave 0..3
    const int q    = lane >> 4;
    const int n16  = lane & 15;

    // XCD swizzle: XCD i -> sw in [128i,128(i+1)) = all tile-pairs of batch i
    const int sw  = (blockIdx.x & 7) * 128 + (blockIdx.x >> 3);
    const int b   = sw >> 7;
    const int typ = (sw >> 4) & 7;
    const int cx  = sw & 15;
    const int x0  = cx * TS;
    const int y00 = 32 * typ, y01 = y00 + 16;

    __shared__ uint32_t Xs[LDSZ];     // [0,5184) X tile; [5184,9792) W

    // ---- staging lane geometry (16x16) ----
    const int srow = lane >> 2;                 // 0..15
    const int scol = (lane & 3) * 4;            // 0,4,8,12
    const bool zc  = (cx == 15) && ((lane & 3) == 3);   // col 255 in .w

    // halo cells: 68 = top 2x18 (c 0..35) + left 16x2 (c 36..67)
    int prowA[2], pcolA[2], h_ldso[2];
    #pragma unroll
    for (int ci = 0; ci < 2; ++ci) {
        const int c = lane + 64 * ci;
        int prow, pcol;
        if (c < 36) { const int hr = (c >= 18) ? 1 : 0; prow = hr; pcol = c - 18 * hr; }
        else        { const int cc = c - 36; prow = KB + (cc >> 1); pcol = cc & 1; }
        prowA[ci] = prow; pcolA[ci] = pcol;
        h_ldso[ci] = prow * RS + pcol;
    }
    const bool h1a = lane < 4;                  // cell1 active

    const float* xb = x    + (size_t)b * C * P * P;
    const float* rb = rbuf + (size_t)b * C * P * KB;
    const float* bb = bbuf + (size_t)b * C * KB * (P + KB);
    const float* basep[3] = { xb, rb, bb };
    const int    psz[3]   = { P * P, P * KB, KB * (P + KB) };

    auto mkh = [&](int y0, const float** bp, int* ps, bool* z) {
        #pragma unroll
        for (int ci = 0; ci < 2; ++ci) {
            const int gr = y0 + prowA[ci], gc = x0 + pcolA[ci];
            int sel, off; bool zz = false;
            if (gr < KB)      { sel = 2; off = gr * (P + KB) + gc; }
            else if (gc < KB) { sel = 1; off = (gr - KB) * KB + gc; }
            else              { sel = 0; off = (gr - KB) * P + (gc - KB);
                                zz = (gc == P + KB - 1); }
            bp[ci] = basep[sel] + off;
            ps[ci] = psz[sel];
            z[ci]  = zz;
        }
    };

    auto ldp = [&](int m, int y0, const float* const* bp, const int* ps,
                   const bool* z, St16& S) {
        const float* pi = xb + (size_t)(2 * m) * (P * P) + (y0 + srow) * P + x0 + scol;
        S.a0 = *(const float4*)pi;
        S.c0 = *(const float4*)(pi + P * P);
        const float* p0 = bp[0] + (size_t)(2 * m) * ps[0];
        S.h0l = z[0] ? 0.f : p0[0];
        S.h0h = z[0] ? 0.f : p0[ps[0]];
        if (h1a) {
            const float* p1 = bp[1] + (size_t)(2 * m) * ps[1];
            S.h1l = z[1] ? 0.f : p1[0];
            S.h1h = z[1] ? 0.f : p1[ps[1]];
        }
    };

    auto stp = [&](int m, const St16& S) {
        float4 a0 = S.a0, c0 = S.c0;
        if (zc) { a0.w = 0.f; c0.w = 0.f; }
        uint2 p0, p1;
        p0.x = pk_bf16(a0.x, c0.x); p0.y = pk_bf16(a0.y, c0.y);
        p1.x = pk_bf16(a0.z, c0.z); p1.y = pk_bf16(a0.w, c0.w);
        uint32_t* base = Xs + m * PL + (srow + KB) * RS + KB + scol;  // 8B aligned
        *(uint2*)(base + 0) = p0;
        *(uint2*)(base + 2) = p1;
        Xs[m * PL + h_ldso[0]] = pk_bf16(S.h0l, S.h0h);
        if (h1a) Xs[m * PL + h_ldso[1]] = pk_bf16(S.h1l, S.h1h);
    };

    const float bvA[2] = { bias[n16], bias[16 + n16] };

    // ---- MFMA sweep for one oc-half of one tile (Bf from LDS: lgkmcnt
    //      only -> in-flight T1 global loads are never drained) ----
    auto sweep = [&](int y0, int oh) {
        Frag Bf[9];
        #pragma unroll
        for (int t = 0; t < 9; ++t)
            *(uint4*)Bf[t].u =
                *(const uint4*)&Xs[WOFF + t * 512 + (oh * 16 + n16) * 16 + q * 4];
        f32x4 acc[4];
        #pragma unroll
        for (int rr = 0; rr < 4; ++rr)
            #pragma unroll
            for (int e = 0; e < 4; ++e) acc[rr][e] = 0.f;

        #pragma unroll
        for (int dr = 0; dr < 6; ++dr) {
            Frag A[3];
            const uint32_t* ap = Xs + (4 * q) * PL + (4 * w + dr) * RS + n16;
            #pragma unroll
            for (int kx = 0; kx < 3; ++kx)
                #pragma unroll
                for (int p = 0; p < 4; ++p)
                    A[kx].u[p] = ap[p * PL + kx];
            #pragma unroll
            for (int ky = 0; ky < 3; ++ky) {
                const int rr = dr - ky;
                if (rr >= 0 && rr < 4) {
                    #pragma unroll
                    for (int kx = 0; kx < 3; ++kx)
                        acc[rr] = __builtin_amdgcn_mfma_f32_16x16x32_bf16(
                                      A[kx].v, Bf[ky * 3 + kx].v, acc[rr], 0, 0, 0);
                }
            }
        }
        const int oc = oh * 16 + n16;
        const float bv = bvA[oh];
        #pragma unroll
        for (int rr = 0; rr < 4; ++rr) {
            float4 v;
            v.x = acc[rr][0] + bv;
            v.y = acc[rr][1] + bv;
            v.z = acc[rr][2] + bv;
            v.w = acc[rr][3] + bv;
            *(float4*)&out[((size_t)(b * C + oc) * P + (y0 + 4 * w + rr)) * P
                           + x0 + 4 * q] = v;
        }
    };

    // ---- 1. W image loads FIRST (oldest in vmcnt FIFO) ----
    const uint4* wp4 = (const uint4*)wpk;          // 1152 uint4
    uint4 wv0 = wp4[tid];
    uint4 wv1 = wp4[256 + tid];
    uint4 wv2 = wp4[512 + tid];
    uint4 wv3 = wp4[768 + tid];
    uint4 wvt;
    const bool wtail = tid < 128;
    if (wtail) wvt = wp4[1024 + tid];

    // ---- 2. T0 loads ----
    const float* bp0[2]; int ps0[2]; bool z0[2];
    mkh(y00, bp0, ps0, z0);
    St16 S0[4];
    #pragma unroll
    for (int k2 = 0; k2 < 4; ++k2) ldp(4 * k2 + w, y00, bp0, ps0, z0, S0[k2]);

    // ---- 3. W -> LDS region (vmcnt waits only W loads) ----
    uint4* xsW = (uint4*)(Xs + WOFF);
    xsW[tid]       = wv0;
    xsW[256 + tid] = wv1;
    xsW[512 + tid] = wv2;
    xsW[768 + tid] = wv3;
    if (wtail) xsW[1024 + tid] = wvt;

    // ---- 4. stage T0 ----
    #pragma unroll
    for (int k2 = 0; k2 < 4; ++k2) stp(4 * k2 + w, S0[k2]);
    __syncthreads();

    // ---- 5. T1 loads interleaved with T0 sweeps (lgkmcnt-only sweeps) ----
    const float* bp1[2]; int ps1[2]; bool z1[2];
    mkh(y01, bp1, ps1, z1);
    St16 S1[4];
    ldp(w,     y01, bp1, ps1, z1, S1[0]);
    ldp(4 + w, y01, bp1, ps1, z1, S1[1]);

    sweep(y00, 0);

    ldp(8 + w, y01, bp1, ps1, z1, S1[2]);

    sweep(y00, 1);

    ldp(12 + w, y01, bp1, ps1, z1, S1[3]);
    __syncthreads();                 // all waves done reading Xs (T0)

    // ---- 6. stage T1 (loads rode out both sweeps), compute T1 ----
    #pragma unroll
    for (int k2 = 0; k2 < 4; ++k2) stp(4 * k2 + w, S1[k2]);
    __syncthreads();

    sweep(y01, 0);
    sweep(y01, 1);
}

extern "C" void kernel_launch(void* const* d_in, const int* in_sizes, int n_in,
                              void* d_out, int out_size, void* d_ws, size_t ws_size,
                              hipStream_t stream) {
    const float* x    = (const float*)d_in[0];
    const float* rbuf = (const float*)d_in[1];
    const float* bbuf = (const float*)d_in[2];
    const float* W    = (const float*)d_in[3];
    const float* bias = (const float*)d_in[4];
    float* out = (float*)d_out;
    uint32_t* wpk = (uint32_t*)d_ws;              // 18432 B used

    pack_w_kernel<<<9, 256, 0, stream>>>(W, wpk);
    conv_mfma<<<1024, 256, 0, stream>>>(x, rbuf, bbuf, wpk, bias, out);
}